// Round 6
// baseline (395.630 us; speedup 1.0000x reference)
//
#include <hip/hip_runtime.h>
#include <hip/hip_bf16.h>
#include <stdint.h>

#define DEV __device__ __forceinline__

typedef float f32x4 __attribute__((ext_vector_type(4)));
typedef float f32x2 __attribute__((ext_vector_type(2)));

constexpr int nB = 64;
constexpr int nL = 1024;
constexpr int nD = 2048;
constexpr int nH = 128;

constexpr int NT = 16;          // L tiles for mean
constexpr int LT = nL / NT;     // 64 rows per tile

constexpr size_t X_ELEMS = (size_t)nB * (size_t)nL * (size_t)nD;  // 134217728

// ---------- math helpers (match JAX/XLA fp32 semantics closely) ----------
DEV float gelu_f(float x) {
  return 0.5f * x * (1.0f + erff(x * 0.7071067811865476f));
}
DEV float gelu_grad_f(float x) {
  return 0.5f * (1.0f + erff(x * 0.7071067811865476f))
       + x * 0.3989422804014327f * expf(-0.5f * x * x);
}
DEV float sigmoid_f(float x) { return 1.0f / (1.0f + expf(-x)); }

DEV uint32_t rotl32(uint32_t v, int r) { return (v << r) | (v >> (32 - r)); }

// unpack bf16 pair packed in a uint32 (lo = bits[15:0], hi = bits[31:16])
DEV float bflo(uint32_t u) { return __uint_as_float(u << 16); }
DEV float bfhi(uint32_t u) { return __uint_as_float(u & 0xFFFF0000u); }

// Threefry-2x32 with key (0,1)  == jax.random.key(1)
DEV void threefry_key01(uint32_t& x0, uint32_t& x1) {
  const uint32_t ks0 = 0u, ks1 = 1u, ks2 = 0x1BD11BDAu ^ 0u ^ 1u;
  x0 += ks0; x1 += ks1;
#define TF_RND(r) { x0 += x1; x1 = rotl32(x1, (r)); x1 ^= x0; }
  TF_RND(13) TF_RND(15) TF_RND(26) TF_RND(6)
  x0 += ks1; x1 += ks2 + 1u;
  TF_RND(17) TF_RND(29) TF_RND(16) TF_RND(24)
  x0 += ks2; x1 += ks0 + 2u;
  TF_RND(13) TF_RND(15) TF_RND(26) TF_RND(6)
  x0 += ks0; x1 += ks1 + 3u;
  TF_RND(17) TF_RND(29) TF_RND(16) TF_RND(24)
  x0 += ks1; x1 += ks2 + 4u;
  TF_RND(13) TF_RND(15) TF_RND(26) TF_RND(6)
  x0 += ks2; x1 += ks0 + 5u;
#undef TF_RND
}

// XLA ErfInv32 (Giles single-precision polynomial)
DEV float erfinv_f32(float x) {
  float w = -log1pf(-x * x);
  float p;
  if (w < 5.0f) {
    w -= 2.5f;
    p = 2.81022636e-08f;
    p = fmaf(p, w, 3.43273939e-07f);
    p = fmaf(p, w, -3.5233877e-06f);
    p = fmaf(p, w, -4.39150654e-06f);
    p = fmaf(p, w, 0.00021858087f);
    p = fmaf(p, w, -0.00125372503f);
    p = fmaf(p, w, -0.00417768164f);
    p = fmaf(p, w, 0.246640727f);
    p = fmaf(p, w, 1.50140941f);
  } else {
    w = sqrtf(w) - 3.0f;
    p = -0.000200214257f;
    p = fmaf(p, w, 0.000100950558f);
    p = fmaf(p, w, 0.00134934322f);
    p = fmaf(p, w, -0.00367342844f);
    p = fmaf(p, w, 0.00573950773f);
    p = fmaf(p, w, -0.0076224613f);
    p = fmaf(p, w, 0.00943887047f);
    p = fmaf(p, w, 1.00167406f);
    p = fmaf(p, w, 2.83297682f);
  }
  return p * x;
}

// jax.random.normal(key(1), (64,2048), f32), element i of row-major flat array
DEV float jax_normal_key1(int i) {
  const uint32_t j = (uint32_t)(i & 0xFFFF);
  uint32_t x0 = j, x1 = j + 65536u;
  threefry_key01(x0, x1);
  const uint32_t bits = (i < 65536) ? x0 : x1;
  const float u01 = __uint_as_float((bits >> 9) | 0x3F800000u) - 1.0f;
  const float lo = __uint_as_float(0xBF7FFFFFu);   // nextafter(-1,0)
  float v = u01 * 2.0f + lo;
  v = fmaxf(lo, v);
  return 1.4142135623730951f * erfinv_f32(v);
}

// ---------- K1: copy x->out + partial mean (blocks 0..1023)
//             + W1 prep to bf16/bf16-T + ctr reset (blocks 1024..1087) ----------
__global__ __launch_bounds__(256) void k_copy_prep(
    const float* __restrict__ x, float* __restrict__ out,
    float* __restrict__ pmean, const float* __restrict__ W1,
    uint16_t* __restrict__ W1b, uint16_t* __restrict__ W1Tb,
    int* __restrict__ ctr)
{
  __shared__ float tile[64][65];
  const int t = threadIdx.x;

  if (blockIdx.x >= (unsigned)(nB * NT)) {
    // ---- prep: W1 f32 -> W1b (same layout) + W1Tb (transposed), bf16 ----
    const int pb = blockIdx.x - nB * NT;   // 0..63
    const int bd = pb & 31;                // d block of 64
    const int bh = pb >> 5;                // h block of 64
    if (pb == 0 && t == 0) ctr[0] = 0;     // reset finalize gate for k_pgd
    const int j = t & 63;
    const int i0 = (t >> 6) * 16;
    for (int ii = 0; ii < 16; ++ii) {
      const int i = i0 + ii;
      const float v = W1[(size_t)(bd * 64 + i) * nH + bh * 64 + j];
      tile[i][j] = v;
      const __hip_bfloat16 hb = __float2bfloat16(v);
      W1b[(size_t)(bd * 64 + i) * nH + bh * 64 + j] =
          *reinterpret_cast<const uint16_t*>(&hb);
    }
    __syncthreads();
    for (int ii = 0; ii < 16; ++ii) {
      const int i = i0 + ii;   // i = h-local, j = d-local
      const __hip_bfloat16 hb = __float2bfloat16(tile[j][i]);
      W1Tb[(size_t)(bh * 64 + i) * nD + bd * 64 + j] =
          *reinterpret_cast<const uint16_t*>(&hb);
    }
    return;
  }

  // ---- copy + partial mean; 4-row unroll = 8 x 16B loads in flight ----
  const int blk = blockIdx.x;            // = b*16 + tile
  const size_t base = (size_t)blk * LT * nD;
  const size_t o0 = (size_t)4 * t;       // d in [0,1024)
  const size_t o1 = 1024 + (size_t)4 * t;
  f32x4 a0 = {0.f, 0.f, 0.f, 0.f};
  f32x4 a1 = {0.f, 0.f, 0.f, 0.f};
  for (int l = 0; l < LT; l += 4) {
    const size_t r0 = base + (size_t)l * nD;
    const size_t r1 = r0 + nD;
    const size_t r2 = r1 + nD;
    const size_t r3 = r2 + nD;
    const f32x4 v0 = *reinterpret_cast<const f32x4*>(x + r0 + o0);
    const f32x4 v1 = *reinterpret_cast<const f32x4*>(x + r0 + o1);
    const f32x4 v2 = *reinterpret_cast<const f32x4*>(x + r1 + o0);
    const f32x4 v3 = *reinterpret_cast<const f32x4*>(x + r1 + o1);
    const f32x4 v4 = *reinterpret_cast<const f32x4*>(x + r2 + o0);
    const f32x4 v5 = *reinterpret_cast<const f32x4*>(x + r2 + o1);
    const f32x4 v6 = *reinterpret_cast<const f32x4*>(x + r3 + o0);
    const f32x4 v7 = *reinterpret_cast<const f32x4*>(x + r3 + o1);
    *reinterpret_cast<f32x4*>(out + r0 + o0) = v0;
    *reinterpret_cast<f32x4*>(out + r0 + o1) = v1;
    *reinterpret_cast<f32x4*>(out + r1 + o0) = v2;
    *reinterpret_cast<f32x4*>(out + r1 + o1) = v3;
    *reinterpret_cast<f32x4*>(out + r2 + o0) = v4;
    *reinterpret_cast<f32x4*>(out + r2 + o1) = v5;
    *reinterpret_cast<f32x4*>(out + r3 + o0) = v6;
    *reinterpret_cast<f32x4*>(out + r3 + o1) = v7;
    a0 += v0; a1 += v1;     // sequential row order: keeps r2/r5 numerics
    a0 += v2; a1 += v3;
    a0 += v4; a1 += v5;
    a0 += v6; a1 += v7;
  }
  float* pm = pmean + (size_t)blk * nD;
  *reinterpret_cast<f32x4*>(pm + o0) = a0;
  *reinterpret_cast<f32x4*>(pm + o1) = a1;
}

// ---------- K2: whole PGD loop, one block per batch; last block finalizes ----
// Iters 0..9 use bf16 weights (only sign(g) matters; clip never binds but is
// kept); final pass (it==10) is round-2's exact fp32 arithmetic.
__global__ __launch_bounds__(1024) void k_pgd(
    const float* __restrict__ W1, const uint16_t* __restrict__ W1b,
    const uint16_t* __restrict__ W1Tb,
    const float* __restrict__ b1, const float* __restrict__ W2,
    const float* __restrict__ b2, const float* __restrict__ pmean,
    const float* __restrict__ pooledG, float* __restrict__ scores,
    int* __restrict__ ctr, float* __restrict__ out,
    const int from_partial)
{
  __shared__ float xaS[nD];
  __shared__ float pooledS[nD];
  __shared__ float redS[32][nH];     // fwd partials (also reused by final pass)
  __shared__ float redB[nD];         // bwd partials (hh==1 half)
  __shared__ float dz1S[nH];
  __shared__ float red2[2];
  __shared__ int lastS;

  const int t = threadIdx.x;       // 0..1023
  const int b = blockIdx.x;        // 0..63

  // init: pooled + threefry noise -> xa0 (2 d per thread)
  {
    float2 pl;
    if (from_partial) {
      float2 s = make_float2(0.f, 0.f);
      for (int nt2 = 0; nt2 < NT; ++nt2) {
        const float2 v = *reinterpret_cast<const float2*>(
            &pmean[((size_t)(b * NT + nt2)) * nD + 2 * t]);
        s.x += v.x; s.y += v.y;
      }
      pl = make_float2(s.x * (1.0f / nL), s.y * (1.0f / nL));
    } else {
      pl = *reinterpret_cast<const float2*>(&pooledG[(size_t)b * nD + 2 * t]);
    }
    pooledS[2 * t]     = pl.x;
    pooledS[2 * t + 1] = pl.y;
    const int i0 = b * nD + 2 * t;
    xaS[2 * t]     = pl.x + 0.01f * jax_normal_key1(i0);
    xaS[2 * t + 1] = pl.y + 0.01f * jax_normal_key1(i0 + 1);
  }

  const float b1t = (t < nH) ? b1[t] : 0.f;
  const float w2t = (t < nH) ? W2[t] : 0.f;
  const float b2s = b2[0];

  __syncthreads();

  // bf16 fwd map: hq = h-quad 0..31, c = d-chunk 0..31 (64 d each)
  const int hq = t & 31;
  const int c  = t >> 5;
  const uint2* __restrict__ w1bq =
      reinterpret_cast<const uint2*>(W1b);      // [d][32 h-quads]
  // bf16 bwd map: dq = d-quad 0..511, hh = h-half 0..1
  const int dqd = t & 511;
  const int hh  = t >> 9;
  const uint2* __restrict__ w1tq =
      reinterpret_cast<const uint2*>(W1Tb);     // [h][512 d-quads]
  // fp32 final map: hf = t&127, dq8 = t>>7 (256 d each)
  const int hf  = t & (nH - 1);
  const int dq8 = t >> 7;

  float sig_last = 0.f;
  for (int it = 0; it <= 10; ++it) {
    float z1 = 0.f;
    if (it < 10) {
      // ---- bf16 forward: uint2 loads (4 h), f32x4 LDS reads, float2 math
      f32x2 a01 = {0.f, 0.f}, a23 = {0.f, 0.f};
      const int dbase = c * 64;
      #pragma unroll 4
      for (int d4 = 0; d4 < 16; ++d4) {
        const int d = dbase + d4 * 4;
        const f32x4 xv4 = *reinterpret_cast<const f32x4*>(&xaS[d]);
        #pragma unroll
        for (int k = 0; k < 4; ++k) {
          const uint2 w = w1bq[(size_t)(d + k) * 32 + hq];
          const f32x2 wa = {bflo(w.x), bfhi(w.x)};
          const f32x2 wb = {bflo(w.y), bfhi(w.y)};
          const float xv = xv4[k];
          a01 += xv * wa;
          a23 += xv * wb;
        }
      }
      f32x4* rp = reinterpret_cast<f32x4*>(&redS[c][4 * hq]);
      *rp = (f32x4){a01.x, a01.y, a23.x, a23.y};
      __syncthreads();
      if (t < nH) {
        #pragma unroll
        for (int c2 = 0; c2 < 32; ++c2) z1 += redS[c2][t];
        z1 += b1t;
      }
    } else {
      // ---- fp32 final forward: round-2 exact arithmetic ----
      float acc = 0.f;
      const float* __restrict__ w1p = W1 + (size_t)(dq8 * 256) * nH + hf;
      #pragma unroll 8
      for (int d = 0; d < 256; ++d)
        acc = fmaf(xaS[dq8 * 256 + d], w1p[(size_t)d * nH], acc);
      redS[dq8][hf] = acc;
      __syncthreads();
      if (t < nH) {
        #pragma unroll
        for (int q2 = 0; q2 < 8; ++q2) z1 += redS[q2][t];
        z1 += b1t;
      }
    }

    if (t < nH) {
      float part = gelu_f(z1) * w2t;
      #pragma unroll
      for (int m = 1; m <= 32; m <<= 1) part += __shfl_xor(part, m, 64);
      if ((t & 63) == 0) red2[t >> 6] = part;
    }
    __syncthreads();

    const float sig = sigmoid_f(red2[0] + red2[1] + b2s);
    if (it == 10) { sig_last = sig; break; }

    if (t < nH) dz1S[t] = sig * (1.f - sig) * w2t * gelu_grad_f(z1);
    __syncthreads();

    // ---- bf16 backward: g = W1 . dz1; uint2 loads (4 d), h split in halves
    f32x2 g01 = {0.f, 0.f}, g23 = {0.f, 0.f};
    #pragma unroll 8
    for (int k = 0; k < 64; ++k) {
      const int h = hh * 64 + k;
      const float dz = dz1S[h];                      // LDS broadcast
      const uint2 w = w1tq[(size_t)h * 512 + dqd];
      const f32x2 wa = {bflo(w.x), bfhi(w.x)};
      const f32x2 wb = {bflo(w.y), bfhi(w.y)};
      g01 += dz * wa;
      g23 += dz * wb;
    }
    if (hh == 1)
      *reinterpret_cast<f32x4*>(&redB[4 * dqd]) =
          (f32x4){g01.x, g01.y, g23.x, g23.y};
    __syncthreads();
    if (hh == 0) {
      const f32x4 o = *reinterpret_cast<const f32x4*>(&redB[4 * dqd]);
      const float g[4] = {g01.x + o.x, g01.y + o.y, g23.x + o.z, g23.y + o.w};
      #pragma unroll
      for (int i = 0; i < 4; ++i) {
        const int d = 4 * dqd + i;
        const float gv = g[i];
        const float sg = (gv > 0.f) ? 1.f : ((gv < 0.f) ? -1.f : 0.f);
        const float pl = pooledS[d];
        float dlt = (xaS[d] - 0.01f * sg) - pl;
        dlt = fminf(fmaxf(dlt, -0.2f), 0.2f);
        xaS[d] = pl + dlt;
      }
    }
    __syncthreads();
  }

  // ---- publish score; last block to finish writes the tail outputs ----
  if (t == 0) {
    scores[b] = sig_last;
    __threadfence();   // release score to device scope
    const int prev = __hip_atomic_fetch_add(ctr, 1, __ATOMIC_ACQ_REL,
                                            __HIP_MEMORY_SCOPE_AGENT);
    lastS = (prev == nB - 1) ? 1 : 0;
  }
  __syncthreads();
  if (lastS && t < nB) {
    const float s = (t == b) ? sig_last
        : __hip_atomic_load(&scores[t], __ATOMIC_RELAXED,
                            __HIP_MEMORY_SCOPE_AGENT);
    out[X_ELEMS + t] = s;                    // worst_score
    out[X_ELEMS + nB + t] = 1.0f - s;        // cert_score
    float m = s;
    #pragma unroll
    for (int o = 32; o > 0; o >>= 1) m = fminf(m, __shfl_xor(m, o, 64));
    if (t == 0) out[X_ELEMS + 2 * nB] = (m < 0.1f) ? 1.0f : 0.0f;  // violated
  }
}

// ---------- fallback helpers (small ws) ----------
__global__ __launch_bounds__(256) void k_zero(float* __restrict__ p, int n) {
  const int i = blockIdx.x * 256 + threadIdx.x;
  if (i < n) p[i] = 0.f;
}

__global__ __launch_bounds__(256) void k_copy_mean_atomic(
    const float* __restrict__ x, float* __restrict__ out,
    float* __restrict__ pooled)
{
  const int blk = blockIdx.x;
  const int b = blk >> 4;
  const int t = threadIdx.x;
  const size_t base = (size_t)blk * LT * nD;
  const size_t o0 = (size_t)4 * t;
  const size_t o1 = 1024 + (size_t)4 * t;
  f32x4 a0 = {0.f, 0.f, 0.f, 0.f};
  f32x4 a1 = {0.f, 0.f, 0.f, 0.f};
  for (int l = 0; l < LT; ++l) {
    const size_t r = base + (size_t)l * nD;
    const f32x4 v0 = *reinterpret_cast<const f32x4*>(x + r + o0);
    const f32x4 v1 = *reinterpret_cast<const f32x4*>(x + r + o1);
    *reinterpret_cast<f32x4*>(out + r + o0) = v0;
    *reinterpret_cast<f32x4*>(out + r + o1) = v1;
    a0 += v0; a1 += v1;
  }
  float* pp = pooled + (size_t)b * nD;
  const float sc = 1.0f / nL;
  atomicAdd(&pp[o0+0], a0.x*sc); atomicAdd(&pp[o0+1], a0.y*sc);
  atomicAdd(&pp[o0+2], a0.z*sc); atomicAdd(&pp[o0+3], a0.w*sc);
  atomicAdd(&pp[o1+0], a1.x*sc); atomicAdd(&pp[o1+1], a1.y*sc);
  atomicAdd(&pp[o1+2], a1.z*sc); atomicAdd(&pp[o1+3], a1.w*sc);
}

__global__ __launch_bounds__(256) void k_prep_only(
    const float* __restrict__ W1, uint16_t* __restrict__ W1b,
    uint16_t* __restrict__ W1Tb, int* __restrict__ ctr)
{
  __shared__ float tile[64][65];
  const int pb = blockIdx.x;
  const int bd = pb & 31;
  const int bh = pb >> 5;
  const int t = threadIdx.x;
  if (pb == 0 && t == 0) ctr[0] = 0;
  const int j = t & 63;
  const int i0 = (t >> 6) * 16;
  for (int ii = 0; ii < 16; ++ii) {
    const int i = i0 + ii;
    const float v = W1[(size_t)(bd * 64 + i) * nH + bh * 64 + j];
    tile[i][j] = v;
    const __hip_bfloat16 hb = __float2bfloat16(v);
    W1b[(size_t)(bd * 64 + i) * nH + bh * 64 + j] =
        *reinterpret_cast<const uint16_t*>(&hb);
  }
  __syncthreads();
  for (int ii = 0; ii < 16; ++ii) {
    const int i = i0 + ii;
    const __hip_bfloat16 hb = __float2bfloat16(tile[j][i]);
    W1Tb[(size_t)(bh * 64 + i) * nD + bd * 64 + j] =
        *reinterpret_cast<const uint16_t*>(&hb);
  }
}

extern "C" void kernel_launch(void* const* d_in, const int* in_sizes, int n_in,
                              void* d_out, int out_size, void* d_ws, size_t ws_size,
                              hipStream_t stream) {
  const float* x  = (const float*)d_in[0];
  const float* W1 = (const float*)d_in[1];
  const float* b1 = (const float*)d_in[2];
  const float* W2 = (const float*)d_in[3];
  const float* b2 = (const float*)d_in[4];
  float* out = (float*)d_out;
  float* ws = (float*)d_ws;

  constexpr size_t PMEAN_ELEMS  = (size_t)nB * NT * nD;   // 2,097,152 f32
  constexpr size_t POOLED_ELEMS = (size_t)nB * nD;        // 131,072 f32
  constexpr size_t W1_ELEMS     = (size_t)nD * nH;        // 262,144
  const size_t primary_bytes =
      PMEAN_ELEMS * 4 + W1_ELEMS * 2 * 2 + nB * 4 + 64;

  if (ws_size >= primary_bytes) {
    float*    pmean  = ws;
    uint16_t* w1b    = (uint16_t*)(ws + PMEAN_ELEMS);
    uint16_t* w1tb   = w1b + W1_ELEMS;
    float*    scores = (float*)(w1tb + W1_ELEMS);
    int*      ctr    = (int*)(scores + nB);

    k_copy_prep<<<nB * NT + 64, 256, 0, stream>>>(x, out, pmean, W1,
                                                  w1b, w1tb, ctr);
    k_pgd<<<nB, 1024, 0, stream>>>(W1, w1b, w1tb, b1, W2, b2,
                                   pmean, nullptr, scores, ctr, out, 1);
  } else {
    float*    pooled = ws;
    uint16_t* w1b    = (uint16_t*)(ws + POOLED_ELEMS);
    uint16_t* w1tb   = w1b + W1_ELEMS;
    float*    scores = (float*)(w1tb + W1_ELEMS);
    int*      ctr    = (int*)(scores + nB);

    k_zero<<<(int)(POOLED_ELEMS + 255) / 256, 256, 0, stream>>>(
        pooled, (int)POOLED_ELEMS);
    k_prep_only<<<64, 256, 0, stream>>>(W1, w1b, w1tb, ctr);
    k_copy_mean_atomic<<<nB * NT, 256, 0, stream>>>(x, out, pooled);
    k_pgd<<<nB, 1024, 0, stream>>>(W1, w1b, w1tb, b1, W2, b2,
                                   nullptr, pooled, scores, ctr, out, 0);
  }
}

// Round 7
// 352.939 us; speedup vs baseline: 1.1210x; 1.1210x over previous
//
#include <hip/hip_runtime.h>
#include <hip/hip_bf16.h>
#include <stdint.h>

#define DEV __device__ __forceinline__

typedef float f32x4 __attribute__((ext_vector_type(4)));

constexpr int nB = 64;
constexpr int nL = 1024;
constexpr int nD = 2048;
constexpr int nH = 128;

constexpr int NT = 16;          // L tiles for mean
constexpr int LT = nL / NT;     // 64 rows per tile

constexpr size_t X_ELEMS = (size_t)nB * (size_t)nL * (size_t)nD;  // 134217728

// ---------- math helpers (match JAX/XLA fp32 semantics closely) ----------
DEV float gelu_f(float x) {
  return 0.5f * x * (1.0f + erff(x * 0.7071067811865476f));
}
DEV float gelu_grad_f(float x) {
  return 0.5f * (1.0f + erff(x * 0.7071067811865476f))
       + x * 0.3989422804014327f * expf(-0.5f * x * x);
}
DEV float sigmoid_f(float x) { return 1.0f / (1.0f + expf(-x)); }

DEV uint32_t rotl32(uint32_t v, int r) { return (v << r) | (v >> (32 - r)); }

DEV float bf2f(uint16_t u) { return __uint_as_float(((uint32_t)u) << 16); }

// Threefry-2x32 with key (0,1)  == jax.random.key(1)
DEV void threefry_key01(uint32_t& x0, uint32_t& x1) {
  const uint32_t ks0 = 0u, ks1 = 1u, ks2 = 0x1BD11BDAu ^ 0u ^ 1u;
  x0 += ks0; x1 += ks1;
#define TF_RND(r) { x0 += x1; x1 = rotl32(x1, (r)); x1 ^= x0; }
  TF_RND(13) TF_RND(15) TF_RND(26) TF_RND(6)
  x0 += ks1; x1 += ks2 + 1u;
  TF_RND(17) TF_RND(29) TF_RND(16) TF_RND(24)
  x0 += ks2; x1 += ks0 + 2u;
  TF_RND(13) TF_RND(15) TF_RND(26) TF_RND(6)
  x0 += ks0; x1 += ks1 + 3u;
  TF_RND(17) TF_RND(29) TF_RND(16) TF_RND(24)
  x0 += ks1; x1 += ks2 + 4u;
  TF_RND(13) TF_RND(15) TF_RND(26) TF_RND(6)
  x0 += ks2; x1 += ks0 + 5u;
#undef TF_RND
}

// XLA ErfInv32 (Giles single-precision polynomial)
DEV float erfinv_f32(float x) {
  float w = -log1pf(-x * x);
  float p;
  if (w < 5.0f) {
    w -= 2.5f;
    p = 2.81022636e-08f;
    p = fmaf(p, w, 3.43273939e-07f);
    p = fmaf(p, w, -3.5233877e-06f);
    p = fmaf(p, w, -4.39150654e-06f);
    p = fmaf(p, w, 0.00021858087f);
    p = fmaf(p, w, -0.00125372503f);
    p = fmaf(p, w, -0.00417768164f);
    p = fmaf(p, w, 0.246640727f);
    p = fmaf(p, w, 1.50140941f);
  } else {
    w = sqrtf(w) - 3.0f;
    p = -0.000200214257f;
    p = fmaf(p, w, 0.000100950558f);
    p = fmaf(p, w, 0.00134934322f);
    p = fmaf(p, w, -0.00367342844f);
    p = fmaf(p, w, 0.00573950773f);
    p = fmaf(p, w, -0.0076224613f);
    p = fmaf(p, w, 0.00943887047f);
    p = fmaf(p, w, 1.00167406f);
    p = fmaf(p, w, 2.83297682f);
  }
  return p * x;
}

// jax.random.normal(key(1), (64,2048), f32), element i of row-major flat array
DEV float jax_normal_key1(int i) {
  const uint32_t j = (uint32_t)(i & 0xFFFF);
  uint32_t x0 = j, x1 = j + 65536u;
  threefry_key01(x0, x1);
  const uint32_t bits = (i < 65536) ? x0 : x1;
  const float u01 = __uint_as_float((bits >> 9) | 0x3F800000u) - 1.0f;
  const float lo = __uint_as_float(0xBF7FFFFFu);   // nextafter(-1,0)
  float v = u01 * 2.0f + lo;
  v = fmaxf(lo, v);
  return 1.4142135623730951f * erfinv_f32(v);
}

// ---------- K1: fused copy x->out + deterministic partial mean ----------
// 512 threads: each thread owns ONE float4 column slice -> 4 blocks/CU x
// 8 waves = 32 waves/CU (max occupancy) for read-latency hiding.
// Per-column accumulation order (row l, then l+1) identical to round 5.
__global__ __launch_bounds__(512) void k_copy_mean(
    const float* __restrict__ x, float* __restrict__ out,
    float* __restrict__ pmean)
{
  const int blk = blockIdx.x;            // = b*16 + tile
  const int t = threadIdx.x;             // 0..511
  const size_t base = (size_t)blk * LT * nD;
  const size_t o = (size_t)4 * t;        // d in [0,2048)
  f32x4 a = {0.f, 0.f, 0.f, 0.f};
  for (int l = 0; l < LT; l += 2) {
    const size_t r0 = base + (size_t)l * nD;
    const size_t r1 = r0 + nD;
    const f32x4 v0 = *reinterpret_cast<const f32x4*>(x + r0 + o);
    const f32x4 v1 = *reinterpret_cast<const f32x4*>(x + r1 + o);
    *reinterpret_cast<f32x4*>(out + r0 + o) = v0;
    *reinterpret_cast<f32x4*>(out + r1 + o) = v1;
    a += v0;                 // row l first, then row l+1: keeps the
    a += v1;                 // sequential-order sum of rounds 1-5
  }
  *reinterpret_cast<f32x4*>(pmean + (size_t)blk * nD + o) = a;
}

// fallback when ws is small: atomic accumulate directly into pooled
__global__ __launch_bounds__(256) void k_copy_mean_atomic(
    const float* __restrict__ x, float* __restrict__ out,
    float* __restrict__ pooled)
{
  const int blk = blockIdx.x;
  const int b = blk >> 4;
  const int t = threadIdx.x;
  const size_t base = (size_t)blk * LT * nD;
  const size_t o0 = (size_t)4 * t;
  const size_t o1 = 1024 + (size_t)4 * t;
  f32x4 a0 = {0.f, 0.f, 0.f, 0.f};
  f32x4 a1 = {0.f, 0.f, 0.f, 0.f};
  for (int l = 0; l < LT; ++l) {
    const size_t r = base + (size_t)l * nD;
    const f32x4 v0 = *reinterpret_cast<const f32x4*>(x + r + o0);
    const f32x4 v1 = *reinterpret_cast<const f32x4*>(x + r + o1);
    *reinterpret_cast<f32x4*>(out + r + o0) = v0;
    *reinterpret_cast<f32x4*>(out + r + o1) = v1;
    a0 += v0; a1 += v1;
  }
  float* pp = pooled + (size_t)b * nD;
  const float sc = 1.0f / nL;
  atomicAdd(&pp[o0+0], a0.x*sc); atomicAdd(&pp[o0+1], a0.y*sc);
  atomicAdd(&pp[o0+2], a0.z*sc); atomicAdd(&pp[o0+3], a0.w*sc);
  atomicAdd(&pp[o1+0], a1.x*sc); atomicAdd(&pp[o1+1], a1.y*sc);
  atomicAdd(&pp[o1+2], a1.z*sc); atomicAdd(&pp[o1+3], a1.w*sc);
}

// ---------- K0: W1 [2048,128] f32 -> W1b [2048,128] bf16 + W1Tb [128,2048] bf16
__global__ __launch_bounds__(256) void k_prep(
    const float* __restrict__ W1, uint16_t* __restrict__ W1b,
    uint16_t* __restrict__ W1Tb)
{
  __shared__ float tile[64][65];
  const int bd = blockIdx.x;   // 0..31  (d block of 64)
  const int bh = blockIdx.y;   // 0..1   (h block of 64)
  const int t = threadIdx.x;
  const int j = t & 63;
  const int i0 = (t >> 6) * 16;
  for (int ii = 0; ii < 16; ++ii) {
    const int i = i0 + ii;
    const float v = W1[(size_t)(bd * 64 + i) * nH + bh * 64 + j];
    tile[i][j] = v;
    const __hip_bfloat16 hb = __float2bfloat16(v);
    W1b[(size_t)(bd * 64 + i) * nH + bh * 64 + j] =
        *reinterpret_cast<const uint16_t*>(&hb);
  }
  __syncthreads();
  for (int ii = 0; ii < 16; ++ii) {
    const int i = i0 + ii;     // i = h-local, j = d-local
    const __hip_bfloat16 hb = __float2bfloat16(tile[j][i]);
    W1Tb[(size_t)(bh * 64 + i) * nD + bd * 64 + j] =
        *reinterpret_cast<const uint16_t*>(&hb);
  }
}

// ---------- K2: whole PGD loop, one block per batch ----------
// Iterations 0..9 use bf16 weights (only sign(g) matters); the final
// scoring pass (it==10) uses fp32 W1 with round-2's exact arithmetic.
__global__ __launch_bounds__(1024) void k_pgd(
    const float* __restrict__ W1, const uint16_t* __restrict__ W1b,
    const uint16_t* __restrict__ W1Tb,
    const float* __restrict__ b1, const float* __restrict__ W2,
    const float* __restrict__ b2, const float* __restrict__ pmean,
    const float* __restrict__ pooledG, float* __restrict__ scores,
    const int from_partial)
{
  __shared__ float xaS[nD];
  __shared__ float pooledS[nD];
  __shared__ float redS[16][nH];
  __shared__ float dz1S[nH];
  __shared__ float red2[2];

  const int t = threadIdx.x;       // 0..1023
  const int b = blockIdx.x;        // 0..63

  // init: pooled + threefry noise -> xa0 (2 d per thread)
  {
    float2 pl;
    if (from_partial) {
      float2 s = make_float2(0.f, 0.f);
      for (int nt2 = 0; nt2 < NT; ++nt2) {
        const float2 v = *reinterpret_cast<const float2*>(
            &pmean[((size_t)(b * NT + nt2)) * nD + 2 * t]);
        s.x += v.x; s.y += v.y;
      }
      pl = make_float2(s.x * (1.0f / nL), s.y * (1.0f / nL));
    } else {
      pl = *reinterpret_cast<const float2*>(&pooledG[(size_t)b * nD + 2 * t]);
    }
    pooledS[2 * t]     = pl.x;
    pooledS[2 * t + 1] = pl.y;
    const int i0 = b * nD + 2 * t;
    xaS[2 * t]     = pl.x + 0.01f * jax_normal_key1(i0);
    xaS[2 * t + 1] = pl.y + 0.01f * jax_normal_key1(i0 + 1);
  }

  const float b1t = (t < nH) ? b1[t] : 0.f;
  const float w2t = (t < nH) ? W2[t] : 0.f;
  const float b2s = b2[0];

  __syncthreads();

  // bf16 fwd mapping: hp = h-pair 0..63, q = d-chunk 0..15 (128 d each)
  const int hp = t & 63;
  const int q  = t >> 6;
  const uint32_t* __restrict__ w1b2 =
      reinterpret_cast<const uint32_t*>(W1b);     // [d][h-pair]
  const uint32_t* __restrict__ w1tb2 =
      reinterpret_cast<const uint32_t*>(W1Tb);    // [h][d-pair]
  // fp32 final mapping: h = t&127, dq = t>>7 (256 d each)
  const int hf = t & (nH - 1);
  const int dq = t >> 7;

  float sig_last = 0.f;
  for (int it = 0; it <= 10; ++it) {
    float z1 = 0.f;
    if (it < 10) {
      // ---- bf16 forward: wave reads 256B/instr contiguous ----
      float accx = 0.f, accy = 0.f;
      const int dbase = q * 128;
      #pragma unroll 8
      for (int dd = 0; dd < 128; ++dd) {
        const float xv = xaS[dbase + dd];              // LDS broadcast
        const uint32_t w = w1b2[(size_t)(dbase + dd) * 64 + hp];
        accx = fmaf(xv, bf2f((uint16_t)(w & 0xFFFF)), accx);
        accy = fmaf(xv, bf2f((uint16_t)(w >> 16)), accy);
      }
      redS[q][2 * hp]     = accx;
      redS[q][2 * hp + 1] = accy;
      __syncthreads();
      if (t < nH) {
        #pragma unroll
        for (int q2 = 0; q2 < 16; ++q2) z1 += redS[q2][t];
        z1 += b1t;
      }
    } else {
      // ---- fp32 final forward: round-2 exact arithmetic ----
      float acc = 0.f;
      const float* __restrict__ w1p = W1 + (size_t)(dq * 256) * nH + hf;
      #pragma unroll 8
      for (int d = 0; d < 256; ++d)
        acc = fmaf(xaS[dq * 256 + d], w1p[(size_t)d * nH], acc);
      redS[dq][hf] = acc;
      __syncthreads();
      if (t < nH) {
        #pragma unroll
        for (int q2 = 0; q2 < 8; ++q2) z1 += redS[q2][t];
        z1 += b1t;
      }
    }

    if (t < nH) {
      float part = gelu_f(z1) * w2t;
      #pragma unroll
      for (int m = 1; m <= 32; m <<= 1) part += __shfl_xor(part, m, 64);
      if ((t & 63) == 0) red2[t >> 6] = part;
    }
    __syncthreads();

    const float sig = sigmoid_f(red2[0] + red2[1] + b2s);
    if (it == 10) { sig_last = sig; break; }

    if (t < nH) dz1S[t] = sig * (1.f - sig) * w2t * gelu_grad_f(z1);
    __syncthreads();

    // ---- bf16 backward: g = W1 . dz1; wave reads 256B/instr ----
    float gx = 0.f, gy = 0.f;
    #pragma unroll 8
    for (int h = 0; h < nH; ++h) {
      const float dz = dz1S[h];                        // LDS broadcast
      const uint32_t w = w1tb2[(size_t)h * 1024 + t];
      gx = fmaf(dz, bf2f((uint16_t)(w & 0xFFFF)), gx);
      gy = fmaf(dz, bf2f((uint16_t)(w >> 16)), gy);
    }
    const float sg0 = (gx > 0.f) ? 1.f : ((gx < 0.f) ? -1.f : 0.f);
    const float sg1 = (gy > 0.f) ? 1.f : ((gy < 0.f) ? -1.f : 0.f);
    const float p0 = pooledS[2 * t], p1 = pooledS[2 * t + 1];
    float d0 = fminf(fmaxf((xaS[2 * t]     - 0.01f * sg0) - p0, -0.2f), 0.2f);
    float d1 = fminf(fmaxf((xaS[2 * t + 1] - 0.01f * sg1) - p1, -0.2f), 0.2f);
    xaS[2 * t]     = p0 + d0;
    xaS[2 * t + 1] = p1 + d1;
    __syncthreads();
  }

  if (t == 0) scores[b] = sig_last;
}

// ---------- zero helper (graph-capture safe; fallback path only) ----------
__global__ __launch_bounds__(256) void k_zero(float* __restrict__ p, int n) {
  const int i = blockIdx.x * 256 + threadIdx.x;
  if (i < n) p[i] = 0.f;
}

// ---------- tail outputs ----------
__global__ __launch_bounds__(64) void k_finalize(
    const float* __restrict__ scores, float* __restrict__ out)
{
  const int t = threadIdx.x;  // 0..63
  const float s = scores[t];
  out[X_ELEMS + t] = s;                    // worst_score
  out[X_ELEMS + nB + t] = 1.0f - s;        // cert_score
  float m = s;
  for (int o = 32; o > 0; o >>= 1) m = fminf(m, __shfl_xor(m, o, 64));
  if (t == 0) out[X_ELEMS + 2 * nB] = (m < 0.1f) ? 1.0f : 0.0f;  // violated
}

extern "C" void kernel_launch(void* const* d_in, const int* in_sizes, int n_in,
                              void* d_out, int out_size, void* d_ws, size_t ws_size,
                              hipStream_t stream) {
  const float* x  = (const float*)d_in[0];
  const float* W1 = (const float*)d_in[1];
  const float* b1 = (const float*)d_in[2];
  const float* W2 = (const float*)d_in[3];
  const float* b2 = (const float*)d_in[4];
  float* out = (float*)d_out;
  float* ws = (float*)d_ws;

  constexpr size_t PMEAN_ELEMS  = (size_t)nB * NT * nD;   // 2,097,152 f32
  constexpr size_t POOLED_ELEMS = (size_t)nB * nD;        // 131,072 f32
  constexpr size_t W1_ELEMS     = (size_t)nD * nH;        // 262,144
  const size_t primary_bytes =
      PMEAN_ELEMS * 4 + W1_ELEMS * 2 * 2 + nB * 4;

  if (ws_size >= primary_bytes) {
    float*    pmean  = ws;
    uint16_t* w1b    = (uint16_t*)(ws + PMEAN_ELEMS);
    uint16_t* w1tb   = w1b + W1_ELEMS;
    float*    scores = (float*)(w1tb + W1_ELEMS);

    k_prep<<<dim3(32, 2), 256, 0, stream>>>(W1, w1b, w1tb);
    k_copy_mean<<<nB * NT, 512, 0, stream>>>(x, out, pmean);
    k_pgd<<<nB, 1024, 0, stream>>>(W1, w1b, w1tb, b1, W2, b2,
                                   pmean, nullptr, scores, 1);
    k_finalize<<<1, 64, 0, stream>>>(scores, out);
  } else {
    float*    pooled = ws;
    uint16_t* w1b    = (uint16_t*)(ws + POOLED_ELEMS);
    uint16_t* w1tb   = w1b + W1_ELEMS;
    float*    scores = (float*)(w1tb + W1_ELEMS);

    k_zero<<<(int)(POOLED_ELEMS + 255) / 256, 256, 0, stream>>>(
        pooled, (int)POOLED_ELEMS);
    k_prep<<<dim3(32, 2), 256, 0, stream>>>(W1, w1b, w1tb);
    k_copy_mean_atomic<<<nB * NT, 256, 0, stream>>>(x, out, pooled);
    k_pgd<<<nB, 1024, 0, stream>>>(W1, w1b, w1tb, b1, W2, b2,
                                   nullptr, pooled, scores, 0);
    k_finalize<<<1, 64, 0, stream>>>(scores, out);
  }
}

// Round 8
// 348.423 us; speedup vs baseline: 1.1355x; 1.0130x over previous
//
#include <hip/hip_runtime.h>
#include <hip/hip_bf16.h>
#include <stdint.h>

#define DEV __device__ __forceinline__

typedef float f32x4 __attribute__((ext_vector_type(4)));

constexpr int nB = 64;
constexpr int nL = 1024;
constexpr int nD = 2048;
constexpr int nH = 128;

constexpr int NT = 16;          // L tiles for mean
constexpr int LT = nL / NT;     // 64 rows per tile

constexpr size_t X_ELEMS = (size_t)nB * (size_t)nL * (size_t)nD;  // 134217728

// ---------- math helpers (match JAX/XLA fp32 semantics closely) ----------
DEV float gelu_f(float x) {
  return 0.5f * x * (1.0f + erff(x * 0.7071067811865476f));
}
DEV float gelu_grad_f(float x) {
  return 0.5f * (1.0f + erff(x * 0.7071067811865476f))
       + x * 0.3989422804014327f * expf(-0.5f * x * x);
}
DEV float sigmoid_f(float x) { return 1.0f / (1.0f + expf(-x)); }

DEV uint32_t rotl32(uint32_t v, int r) { return (v << r) | (v >> (32 - r)); }

DEV float bf2f(uint16_t u) { return __uint_as_float(((uint32_t)u) << 16); }

// Threefry-2x32 with key (0,1)  == jax.random.key(1)
DEV void threefry_key01(uint32_t& x0, uint32_t& x1) {
  const uint32_t ks0 = 0u, ks1 = 1u, ks2 = 0x1BD11BDAu ^ 0u ^ 1u;
  x0 += ks0; x1 += ks1;
#define TF_RND(r) { x0 += x1; x1 = rotl32(x1, (r)); x1 ^= x0; }
  TF_RND(13) TF_RND(15) TF_RND(26) TF_RND(6)
  x0 += ks1; x1 += ks2 + 1u;
  TF_RND(17) TF_RND(29) TF_RND(16) TF_RND(24)
  x0 += ks2; x1 += ks0 + 2u;
  TF_RND(13) TF_RND(15) TF_RND(26) TF_RND(6)
  x0 += ks0; x1 += ks1 + 3u;
  TF_RND(17) TF_RND(29) TF_RND(16) TF_RND(24)
  x0 += ks1; x1 += ks2 + 4u;
  TF_RND(13) TF_RND(15) TF_RND(26) TF_RND(6)
  x0 += ks2; x1 += ks0 + 5u;
#undef TF_RND
}

// XLA ErfInv32 (Giles single-precision polynomial)
DEV float erfinv_f32(float x) {
  float w = -log1pf(-x * x);
  float p;
  if (w < 5.0f) {
    w -= 2.5f;
    p = 2.81022636e-08f;
    p = fmaf(p, w, 3.43273939e-07f);
    p = fmaf(p, w, -3.5233877e-06f);
    p = fmaf(p, w, -4.39150654e-06f);
    p = fmaf(p, w, 0.00021858087f);
    p = fmaf(p, w, -0.00125372503f);
    p = fmaf(p, w, -0.00417768164f);
    p = fmaf(p, w, 0.246640727f);
    p = fmaf(p, w, 1.50140941f);
  } else {
    w = sqrtf(w) - 3.0f;
    p = -0.000200214257f;
    p = fmaf(p, w, 0.000100950558f);
    p = fmaf(p, w, 0.00134934322f);
    p = fmaf(p, w, -0.00367342844f);
    p = fmaf(p, w, 0.00573950773f);
    p = fmaf(p, w, -0.0076224613f);
    p = fmaf(p, w, 0.00943887047f);
    p = fmaf(p, w, 1.00167406f);
    p = fmaf(p, w, 2.83297682f);
  }
  return p * x;
}

// jax.random.normal(key(1), (64,2048), f32), element i of row-major flat array
DEV float jax_normal_key1(int i) {
  const uint32_t j = (uint32_t)(i & 0xFFFF);
  uint32_t x0 = j, x1 = j + 65536u;
  threefry_key01(x0, x1);
  const uint32_t bits = (i < 65536) ? x0 : x1;
  const float u01 = __uint_as_float((bits >> 9) | 0x3F800000u) - 1.0f;
  const float lo = __uint_as_float(0xBF7FFFFFu);   // nextafter(-1,0)
  float v = u01 * 2.0f + lo;
  v = fmaxf(lo, v);
  return 1.4142135623730951f * erfinv_f32(v);
}

// ---------- K1: fused copy x->out + deterministic partial mean ----------
// Loads NORMAL (keep x's ~256MB L3 residency across replays -> FETCH ~274MB).
// Stores NONTEMPORAL: out lines are write-once; bypassing L2/L3 allocation
// stops the write stream from evicting x and matches the fill kernels'
// 6.7 TB/s pure-write behavior.
__global__ __launch_bounds__(512) void k_copy_mean(
    const float* __restrict__ x, float* __restrict__ out,
    float* __restrict__ pmean)
{
  const int blk = blockIdx.x;            // = b*16 + tile
  const int t = threadIdx.x;             // 0..511
  const size_t base = (size_t)blk * LT * nD;
  const size_t o = (size_t)4 * t;        // d in [0,2048)
  f32x4 a = {0.f, 0.f, 0.f, 0.f};
  for (int l = 0; l < LT; l += 2) {
    const size_t r0 = base + (size_t)l * nD;
    const size_t r1 = r0 + nD;
    const f32x4 v0 = *reinterpret_cast<const f32x4*>(x + r0 + o);
    const f32x4 v1 = *reinterpret_cast<const f32x4*>(x + r1 + o);
    __builtin_nontemporal_store(v0, reinterpret_cast<f32x4*>(out + r0 + o));
    __builtin_nontemporal_store(v1, reinterpret_cast<f32x4*>(out + r1 + o));
    a += v0;                 // row l first, then row l+1: keeps the
    a += v1;                 // sequential-order sum of rounds 1-5
  }
  *reinterpret_cast<f32x4*>(pmean + (size_t)blk * nD + o) = a;
}

// fallback when ws is small: atomic accumulate directly into pooled
__global__ __launch_bounds__(256) void k_copy_mean_atomic(
    const float* __restrict__ x, float* __restrict__ out,
    float* __restrict__ pooled)
{
  const int blk = blockIdx.x;
  const int b = blk >> 4;
  const int t = threadIdx.x;
  const size_t base = (size_t)blk * LT * nD;
  const size_t o0 = (size_t)4 * t;
  const size_t o1 = 1024 + (size_t)4 * t;
  f32x4 a0 = {0.f, 0.f, 0.f, 0.f};
  f32x4 a1 = {0.f, 0.f, 0.f, 0.f};
  for (int l = 0; l < LT; ++l) {
    const size_t r = base + (size_t)l * nD;
    const f32x4 v0 = *reinterpret_cast<const f32x4*>(x + r + o0);
    const f32x4 v1 = *reinterpret_cast<const f32x4*>(x + r + o1);
    *reinterpret_cast<f32x4*>(out + r + o0) = v0;
    *reinterpret_cast<f32x4*>(out + r + o1) = v1;
    a0 += v0; a1 += v1;
  }
  float* pp = pooled + (size_t)b * nD;
  const float sc = 1.0f / nL;
  atomicAdd(&pp[o0+0], a0.x*sc); atomicAdd(&pp[o0+1], a0.y*sc);
  atomicAdd(&pp[o0+2], a0.z*sc); atomicAdd(&pp[o0+3], a0.w*sc);
  atomicAdd(&pp[o1+0], a1.x*sc); atomicAdd(&pp[o1+1], a1.y*sc);
  atomicAdd(&pp[o1+2], a1.z*sc); atomicAdd(&pp[o1+3], a1.w*sc);
}

// ---------- K0: W1 [2048,128] f32 -> W1b [2048,128] bf16 + W1Tb [128,2048] bf16
__global__ __launch_bounds__(256) void k_prep(
    const float* __restrict__ W1, uint16_t* __restrict__ W1b,
    uint16_t* __restrict__ W1Tb)
{
  __shared__ float tile[64][65];
  const int bd = blockIdx.x;   // 0..31  (d block of 64)
  const int bh = blockIdx.y;   // 0..1   (h block of 64)
  const int t = threadIdx.x;
  const int j = t & 63;
  const int i0 = (t >> 6) * 16;
  for (int ii = 0; ii < 16; ++ii) {
    const int i = i0 + ii;
    const float v = W1[(size_t)(bd * 64 + i) * nH + bh * 64 + j];
    tile[i][j] = v;
    const __hip_bfloat16 hb = __float2bfloat16(v);
    W1b[(size_t)(bd * 64 + i) * nH + bh * 64 + j] =
        *reinterpret_cast<const uint16_t*>(&hb);
  }
  __syncthreads();
  for (int ii = 0; ii < 16; ++ii) {
    const int i = i0 + ii;     // i = h-local, j = d-local
    const __hip_bfloat16 hb = __float2bfloat16(tile[j][i]);
    W1Tb[(size_t)(bh * 64 + i) * nD + bd * 64 + j] =
        *reinterpret_cast<const uint16_t*>(&hb);
  }
}

// ---------- K2: whole PGD loop, one block per batch ----------
// Iterations 0..9 use bf16 weights (only sign(g) matters); the final
// scoring pass (it==10) uses fp32 W1 with round-2's exact arithmetic.
__global__ __launch_bounds__(1024) void k_pgd(
    const float* __restrict__ W1, const uint16_t* __restrict__ W1b,
    const uint16_t* __restrict__ W1Tb,
    const float* __restrict__ b1, const float* __restrict__ W2,
    const float* __restrict__ b2, const float* __restrict__ pmean,
    const float* __restrict__ pooledG, float* __restrict__ scores,
    const int from_partial)
{
  __shared__ float xaS[nD];
  __shared__ float pooledS[nD];
  __shared__ float redS[16][nH];
  __shared__ float dz1S[nH];
  __shared__ float red2[2];

  const int t = threadIdx.x;       // 0..1023
  const int b = blockIdx.x;        // 0..63

  // init: pooled + threefry noise -> xa0 (2 d per thread)
  {
    float2 pl;
    if (from_partial) {
      float2 s = make_float2(0.f, 0.f);
      for (int nt2 = 0; nt2 < NT; ++nt2) {
        const float2 v = *reinterpret_cast<const float2*>(
            &pmean[((size_t)(b * NT + nt2)) * nD + 2 * t]);
        s.x += v.x; s.y += v.y;
      }
      pl = make_float2(s.x * (1.0f / nL), s.y * (1.0f / nL));
    } else {
      pl = *reinterpret_cast<const float2*>(&pooledG[(size_t)b * nD + 2 * t]);
    }
    pooledS[2 * t]     = pl.x;
    pooledS[2 * t + 1] = pl.y;
    const int i0 = b * nD + 2 * t;
    xaS[2 * t]     = pl.x + 0.01f * jax_normal_key1(i0);
    xaS[2 * t + 1] = pl.y + 0.01f * jax_normal_key1(i0 + 1);
  }

  const float b1t = (t < nH) ? b1[t] : 0.f;
  const float w2t = (t < nH) ? W2[t] : 0.f;
  const float b2s = b2[0];

  __syncthreads();

  // bf16 fwd mapping: hp = h-pair 0..63, q = d-chunk 0..15 (128 d each)
  const int hp = t & 63;
  const int q  = t >> 6;
  const uint32_t* __restrict__ w1b2 =
      reinterpret_cast<const uint32_t*>(W1b);     // [d][h-pair]
  const uint32_t* __restrict__ w1tb2 =
      reinterpret_cast<const uint32_t*>(W1Tb);    // [h][d-pair]
  // fp32 final mapping: h = t&127, dq = t>>7 (256 d each)
  const int hf = t & (nH - 1);
  const int dq = t >> 7;

  float sig_last = 0.f;
  for (int it = 0; it <= 10; ++it) {
    float z1 = 0.f;
    if (it < 10) {
      // ---- bf16 forward: wave reads 256B/instr contiguous ----
      float accx = 0.f, accy = 0.f;
      const int dbase = q * 128;
      #pragma unroll 8
      for (int dd = 0; dd < 128; ++dd) {
        const float xv = xaS[dbase + dd];              // LDS broadcast
        const uint32_t w = w1b2[(size_t)(dbase + dd) * 64 + hp];
        accx = fmaf(xv, bf2f((uint16_t)(w & 0xFFFF)), accx);
        accy = fmaf(xv, bf2f((uint16_t)(w >> 16)), accy);
      }
      redS[q][2 * hp]     = accx;
      redS[q][2 * hp + 1] = accy;
      __syncthreads();
      if (t < nH) {
        #pragma unroll
        for (int q2 = 0; q2 < 16; ++q2) z1 += redS[q2][t];
        z1 += b1t;
      }
    } else {
      // ---- fp32 final forward: round-2 exact arithmetic ----
      float acc = 0.f;
      const float* __restrict__ w1p = W1 + (size_t)(dq * 256) * nH + hf;
      #pragma unroll 8
      for (int d = 0; d < 256; ++d)
        acc = fmaf(xaS[dq * 256 + d], w1p[(size_t)d * nH], acc);
      redS[dq][hf] = acc;
      __syncthreads();
      if (t < nH) {
        #pragma unroll
        for (int q2 = 0; q2 < 8; ++q2) z1 += redS[q2][t];
        z1 += b1t;
      }
    }

    if (t < nH) {
      float part = gelu_f(z1) * w2t;
      #pragma unroll
      for (int m = 1; m <= 32; m <<= 1) part += __shfl_xor(part, m, 64);
      if ((t & 63) == 0) red2[t >> 6] = part;
    }
    __syncthreads();

    const float sig = sigmoid_f(red2[0] + red2[1] + b2s);
    if (it == 10) { sig_last = sig; break; }

    if (t < nH) dz1S[t] = sig * (1.f - sig) * w2t * gelu_grad_f(z1);
    __syncthreads();

    // ---- bf16 backward: g = W1 . dz1; wave reads 256B/instr ----
    float gx = 0.f, gy = 0.f;
    #pragma unroll 8
    for (int h = 0; h < nH; ++h) {
      const float dz = dz1S[h];                        // LDS broadcast
      const uint32_t w = w1tb2[(size_t)h * 1024 + t];
      gx = fmaf(dz, bf2f((uint16_t)(w & 0xFFFF)), gx);
      gy = fmaf(dz, bf2f((uint16_t)(w >> 16)), gy);
    }
    const float sg0 = (gx > 0.f) ? 1.f : ((gx < 0.f) ? -1.f : 0.f);
    const float sg1 = (gy > 0.f) ? 1.f : ((gy < 0.f) ? -1.f : 0.f);
    const float p0 = pooledS[2 * t], p1 = pooledS[2 * t + 1];
    float d0 = fminf(fmaxf((xaS[2 * t]     - 0.01f * sg0) - p0, -0.2f), 0.2f);
    float d1 = fminf(fmaxf((xaS[2 * t + 1] - 0.01f * sg1) - p1, -0.2f), 0.2f);
    xaS[2 * t]     = p0 + d0;
    xaS[2 * t + 1] = p1 + d1;
    __syncthreads();
  }

  if (t == 0) scores[b] = sig_last;
}

// ---------- zero helper (graph-capture safe; fallback path only) ----------
__global__ __launch_bounds__(256) void k_zero(float* __restrict__ p, int n) {
  const int i = blockIdx.x * 256 + threadIdx.x;
  if (i < n) p[i] = 0.f;
}

// ---------- tail outputs ----------
__global__ __launch_bounds__(64) void k_finalize(
    const float* __restrict__ scores, float* __restrict__ out)
{
  const int t = threadIdx.x;  // 0..63
  const float s = scores[t];
  out[X_ELEMS + t] = s;                    // worst_score
  out[X_ELEMS + nB + t] = 1.0f - s;        // cert_score
  float m = s;
  for (int o = 32; o > 0; o >>= 1) m = fminf(m, __shfl_xor(m, o, 64));
  if (t == 0) out[X_ELEMS + 2 * nB] = (m < 0.1f) ? 1.0f : 0.0f;  // violated
}

extern "C" void kernel_launch(void* const* d_in, const int* in_sizes, int n_in,
                              void* d_out, int out_size, void* d_ws, size_t ws_size,
                              hipStream_t stream) {
  const float* x  = (const float*)d_in[0];
  const float* W1 = (const float*)d_in[1];
  const float* b1 = (const float*)d_in[2];
  const float* W2 = (const float*)d_in[3];
  const float* b2 = (const float*)d_in[4];
  float* out = (float*)d_out;
  float* ws = (float*)d_ws;

  constexpr size_t PMEAN_ELEMS  = (size_t)nB * NT * nD;   // 2,097,152 f32
  constexpr size_t POOLED_ELEMS = (size_t)nB * nD;        // 131,072 f32
  constexpr size_t W1_ELEMS     = (size_t)nD * nH;        // 262,144
  const size_t primary_bytes =
      PMEAN_ELEMS * 4 + W1_ELEMS * 2 * 2 + nB * 4;

  if (ws_size >= primary_bytes) {
    float*    pmean  = ws;
    uint16_t* w1b    = (uint16_t*)(ws + PMEAN_ELEMS);
    uint16_t* w1tb   = w1b + W1_ELEMS;
    float*    scores = (float*)(w1tb + W1_ELEMS);

    k_prep<<<dim3(32, 2), 256, 0, stream>>>(W1, w1b, w1tb);
    k_copy_mean<<<nB * NT, 512, 0, stream>>>(x, out, pmean);
    k_pgd<<<nB, 1024, 0, stream>>>(W1, w1b, w1tb, b1, W2, b2,
                                   pmean, nullptr, scores, 1);
    k_finalize<<<1, 64, 0, stream>>>(scores, out);
  } else {
    float*    pooled = ws;
    uint16_t* w1b    = (uint16_t*)(ws + POOLED_ELEMS);
    uint16_t* w1tb   = w1b + W1_ELEMS;
    float*    scores = (float*)(w1tb + W1_ELEMS);

    k_zero<<<(int)(POOLED_ELEMS + 255) / 256, 256, 0, stream>>>(
        pooled, (int)POOLED_ELEMS);
    k_prep<<<dim3(32, 2), 256, 0, stream>>>(W1, w1b, w1tb);
    k_copy_mean_atomic<<<nB * NT, 256, 0, stream>>>(x, out, pooled);
    k_pgd<<<nB, 1024, 0, stream>>>(W1, w1b, w1tb, b1, W2, b2,
                                   nullptr, pooled, scores, 0);
    k_finalize<<<1, 64, 0, stream>>>(scores, out);
  }
}

// Round 9
// 317.387 us; speedup vs baseline: 1.2465x; 1.0978x over previous
//
#include <hip/hip_runtime.h>
#include <hip/hip_bf16.h>
#include <stdint.h>

#define DEV __device__ __forceinline__

typedef float f32x4 __attribute__((ext_vector_type(4)));
typedef float f32x2 __attribute__((ext_vector_type(2)));

constexpr int nB = 64;
constexpr int nL = 1024;
constexpr int nD = 2048;
constexpr int nH = 128;

constexpr int NT = 16;          // L tiles for mean
constexpr int LT = nL / NT;     // 64 rows per tile

constexpr size_t X_ELEMS = (size_t)nB * (size_t)nL * (size_t)nD;  // 134217728

// ---------- math helpers (match JAX/XLA fp32 semantics closely) ----------
DEV float gelu_f(float x) {
  return 0.5f * x * (1.0f + erff(x * 0.7071067811865476f));
}
DEV float gelu_grad_f(float x) {
  return 0.5f * (1.0f + erff(x * 0.7071067811865476f))
       + x * 0.3989422804014327f * expf(-0.5f * x * x);
}
DEV float sigmoid_f(float x) { return 1.0f / (1.0f + expf(-x)); }

DEV uint32_t rotl32(uint32_t v, int r) { return (v << r) | (v >> (32 - r)); }

DEV float bflo(uint32_t u) { return __uint_as_float(u << 16); }
DEV float bfhi(uint32_t u) { return __uint_as_float(u & 0xFFFF0000u); }

// Threefry-2x32 with key (0,1)  == jax.random.key(1)
DEV void threefry_key01(uint32_t& x0, uint32_t& x1) {
  const uint32_t ks0 = 0u, ks1 = 1u, ks2 = 0x1BD11BDAu ^ 0u ^ 1u;
  x0 += ks0; x1 += ks1;
#define TF_RND(r) { x0 += x1; x1 = rotl32(x1, (r)); x1 ^= x0; }
  TF_RND(13) TF_RND(15) TF_RND(26) TF_RND(6)
  x0 += ks1; x1 += ks2 + 1u;
  TF_RND(17) TF_RND(29) TF_RND(16) TF_RND(24)
  x0 += ks2; x1 += ks0 + 2u;
  TF_RND(13) TF_RND(15) TF_RND(26) TF_RND(6)
  x0 += ks0; x1 += ks1 + 3u;
  TF_RND(17) TF_RND(29) TF_RND(16) TF_RND(24)
  x0 += ks1; x1 += ks2 + 4u;
  TF_RND(13) TF_RND(15) TF_RND(26) TF_RND(6)
  x0 += ks2; x1 += ks0 + 5u;
#undef TF_RND
}

// XLA ErfInv32 (Giles single-precision polynomial)
DEV float erfinv_f32(float x) {
  float w = -log1pf(-x * x);
  float p;
  if (w < 5.0f) {
    w -= 2.5f;
    p = 2.81022636e-08f;
    p = fmaf(p, w, 3.43273939e-07f);
    p = fmaf(p, w, -3.5233877e-06f);
    p = fmaf(p, w, -4.39150654e-06f);
    p = fmaf(p, w, 0.00021858087f);
    p = fmaf(p, w, -0.00125372503f);
    p = fmaf(p, w, -0.00417768164f);
    p = fmaf(p, w, 0.246640727f);
    p = fmaf(p, w, 1.50140941f);
  } else {
    w = sqrtf(w) - 3.0f;
    p = -0.000200214257f;
    p = fmaf(p, w, 0.000100950558f);
    p = fmaf(p, w, 0.00134934322f);
    p = fmaf(p, w, -0.00367342844f);
    p = fmaf(p, w, 0.00573950773f);
    p = fmaf(p, w, -0.0076224613f);
    p = fmaf(p, w, 0.00943887047f);
    p = fmaf(p, w, 1.00167406f);
    p = fmaf(p, w, 2.83297682f);
  }
  return p * x;
}

// jax.random.normal(key(1), (64,2048), f32), element i of row-major flat array
DEV float jax_normal_key1(int i) {
  const uint32_t j = (uint32_t)(i & 0xFFFF);
  uint32_t x0 = j, x1 = j + 65536u;
  threefry_key01(x0, x1);
  const uint32_t bits = (i < 65536) ? x0 : x1;
  const float u01 = __uint_as_float((bits >> 9) | 0x3F800000u) - 1.0f;
  const float lo = __uint_as_float(0xBF7FFFFFu);   // nextafter(-1,0)
  float v = u01 * 2.0f + lo;
  v = fmaxf(lo, v);
  return 1.4142135623730951f * erfinv_f32(v);
}

// ---------- K1: fused copy x->out + deterministic partial mean ----------
// Fully nontemporal stream: x is read exactly once per replay (and the
// inter-replay reset fills wipe L3 anyway), out is write-once. Skipping
// L2/L3 allocation in BOTH directions removes fill/evict overhead.
__global__ __launch_bounds__(512) void k_copy_mean(
    const float* __restrict__ x, float* __restrict__ out,
    float* __restrict__ pmean)
{
  const int blk = blockIdx.x;            // = b*16 + tile
  const int t = threadIdx.x;             // 0..511
  const size_t base = (size_t)blk * LT * nD;
  const size_t o = (size_t)4 * t;        // d in [0,2048)
  f32x4 a = {0.f, 0.f, 0.f, 0.f};
  for (int l = 0; l < LT; l += 2) {
    const size_t r0 = base + (size_t)l * nD;
    const size_t r1 = r0 + nD;
    const f32x4 v0 = __builtin_nontemporal_load(
        reinterpret_cast<const f32x4*>(x + r0 + o));
    const f32x4 v1 = __builtin_nontemporal_load(
        reinterpret_cast<const f32x4*>(x + r1 + o));
    __builtin_nontemporal_store(v0, reinterpret_cast<f32x4*>(out + r0 + o));
    __builtin_nontemporal_store(v1, reinterpret_cast<f32x4*>(out + r1 + o));
    a += v0;                 // row l first, then row l+1: keeps the
    a += v1;                 // sequential-order sum of rounds 1-8
  }
  *reinterpret_cast<f32x4*>(pmean + (size_t)blk * nD + o) = a;
}

// fallback when ws is small: atomic accumulate directly into pooled
__global__ __launch_bounds__(256) void k_copy_mean_atomic(
    const float* __restrict__ x, float* __restrict__ out,
    float* __restrict__ pooled)
{
  const int blk = blockIdx.x;
  const int b = blk >> 4;
  const int t = threadIdx.x;
  const size_t base = (size_t)blk * LT * nD;
  const size_t o0 = (size_t)4 * t;
  const size_t o1 = 1024 + (size_t)4 * t;
  f32x4 a0 = {0.f, 0.f, 0.f, 0.f};
  f32x4 a1 = {0.f, 0.f, 0.f, 0.f};
  for (int l = 0; l < LT; ++l) {
    const size_t r = base + (size_t)l * nD;
    const f32x4 v0 = *reinterpret_cast<const f32x4*>(x + r + o0);
    const f32x4 v1 = *reinterpret_cast<const f32x4*>(x + r + o1);
    *reinterpret_cast<f32x4*>(out + r + o0) = v0;
    *reinterpret_cast<f32x4*>(out + r + o1) = v1;
    a0 += v0; a1 += v1;
  }
  float* pp = pooled + (size_t)b * nD;
  const float sc = 1.0f / nL;
  atomicAdd(&pp[o0+0], a0.x*sc); atomicAdd(&pp[o0+1], a0.y*sc);
  atomicAdd(&pp[o0+2], a0.z*sc); atomicAdd(&pp[o0+3], a0.w*sc);
  atomicAdd(&pp[o1+0], a1.x*sc); atomicAdd(&pp[o1+1], a1.y*sc);
  atomicAdd(&pp[o1+2], a1.z*sc); atomicAdd(&pp[o1+3], a1.w*sc);
}

// ---------- K0: W1 [2048,128] f32 -> W1b [2048,128] bf16 + W1Tb [128,2048] bf16
__global__ __launch_bounds__(256) void k_prep(
    const float* __restrict__ W1, uint16_t* __restrict__ W1b,
    uint16_t* __restrict__ W1Tb)
{
  __shared__ float tile[64][65];
  const int bd = blockIdx.x;   // 0..31  (d block of 64)
  const int bh = blockIdx.y;   // 0..1   (h block of 64)
  const int t = threadIdx.x;
  const int j = t & 63;
  const int i0 = (t >> 6) * 16;
  for (int ii = 0; ii < 16; ++ii) {
    const int i = i0 + ii;
    const float v = W1[(size_t)(bd * 64 + i) * nH + bh * 64 + j];
    tile[i][j] = v;
    const __hip_bfloat16 hb = __float2bfloat16(v);
    W1b[(size_t)(bd * 64 + i) * nH + bh * 64 + j] =
        *reinterpret_cast<const uint16_t*>(&hb);
  }
  __syncthreads();
  for (int ii = 0; ii < 16; ++ii) {
    const int i = i0 + ii;     // i = h-local, j = d-local
    const __hip_bfloat16 hb = __float2bfloat16(tile[j][i]);
    W1Tb[(size_t)(bh * 64 + i) * nD + bd * 64 + j] =
        *reinterpret_cast<const uint16_t*>(&hb);
  }
}

// ---------- K2: whole PGD loop, one block per batch ----------
// Iterations 0..9 use bf16 weights (only sign(g) matters); the final
// scoring pass (it==10) uses fp32 W1 with round-2's exact arithmetic.
// Inner loops 4-unrolled: ds_read_b128 broadcast + f32x2 pk-fma math;
// per-d (per-h) accumulation order identical to round 8 -> bit-same result.
__global__ __launch_bounds__(1024) void k_pgd(
    const float* __restrict__ W1, const uint16_t* __restrict__ W1b,
    const uint16_t* __restrict__ W1Tb,
    const float* __restrict__ b1, const float* __restrict__ W2,
    const float* __restrict__ b2, const float* __restrict__ pmean,
    const float* __restrict__ pooledG, float* __restrict__ scores,
    const int from_partial)
{
  __shared__ float xaS[nD];
  __shared__ float pooledS[nD];
  __shared__ float redS[16][nH];
  __shared__ float dz1S[nH];
  __shared__ float red2[2];

  const int t = threadIdx.x;       // 0..1023
  const int b = blockIdx.x;        // 0..63

  // init: pooled + threefry noise -> xa0 (2 d per thread)
  {
    float2 pl;
    if (from_partial) {
      float2 s = make_float2(0.f, 0.f);
      for (int nt2 = 0; nt2 < NT; ++nt2) {
        const float2 v = *reinterpret_cast<const float2*>(
            &pmean[((size_t)(b * NT + nt2)) * nD + 2 * t]);
        s.x += v.x; s.y += v.y;
      }
      pl = make_float2(s.x * (1.0f / nL), s.y * (1.0f / nL));
    } else {
      pl = *reinterpret_cast<const float2*>(&pooledG[(size_t)b * nD + 2 * t]);
    }
    pooledS[2 * t]     = pl.x;
    pooledS[2 * t + 1] = pl.y;
    const int i0 = b * nD + 2 * t;
    xaS[2 * t]     = pl.x + 0.01f * jax_normal_key1(i0);
    xaS[2 * t + 1] = pl.y + 0.01f * jax_normal_key1(i0 + 1);
  }

  const float b1t = (t < nH) ? b1[t] : 0.f;
  const float w2t = (t < nH) ? W2[t] : 0.f;
  const float b2s = b2[0];

  __syncthreads();

  // bf16 fwd mapping: hp = h-pair 0..63, q = d-chunk 0..15 (128 d each)
  const int hp = t & 63;
  const int q  = t >> 6;
  const uint32_t* __restrict__ w1b2 =
      reinterpret_cast<const uint32_t*>(W1b);     // [d][h-pair]
  const uint32_t* __restrict__ w1tb2 =
      reinterpret_cast<const uint32_t*>(W1Tb);    // [h][d-pair]
  // fp32 final mapping: h = t&127, dq = t>>7 (256 d each)
  const int hf = t & (nH - 1);
  const int dq = t >> 7;

  float sig_last = 0.f;
  for (int it = 0; it <= 10; ++it) {
    float z1 = 0.f;
    if (it < 10) {
      // ---- bf16 forward: 4-d unroll, b128 LDS broadcast, pk-fma ----
      f32x2 acc2 = {0.f, 0.f};
      const int dbase = q * 128;
      #pragma unroll 4
      for (int d4 = 0; d4 < 32; ++d4) {
        const int d = dbase + 4 * d4;
        const f32x4 xv4 = *reinterpret_cast<const f32x4*>(&xaS[d]);
        #pragma unroll
        for (int k = 0; k < 4; ++k) {
          const uint32_t w = w1b2[(size_t)(d + k) * 64 + hp];
          const f32x2 wv = {bflo(w), bfhi(w)};
          acc2 += xv4[k] * wv;
        }
      }
      redS[q][2 * hp]     = acc2.x;
      redS[q][2 * hp + 1] = acc2.y;
      __syncthreads();
      if (t < nH) {
        #pragma unroll
        for (int q2 = 0; q2 < 16; ++q2) z1 += redS[q2][t];
        z1 += b1t;
      }
    } else {
      // ---- fp32 final forward: round-2 exact arithmetic ----
      float acc = 0.f;
      const float* __restrict__ w1p = W1 + (size_t)(dq * 256) * nH + hf;
      #pragma unroll 8
      for (int d = 0; d < 256; ++d)
        acc = fmaf(xaS[dq * 256 + d], w1p[(size_t)d * nH], acc);
      redS[dq][hf] = acc;
      __syncthreads();
      if (t < nH) {
        #pragma unroll
        for (int q2 = 0; q2 < 8; ++q2) z1 += redS[q2][t];
        z1 += b1t;
      }
    }

    if (t < nH) {
      float part = gelu_f(z1) * w2t;
      #pragma unroll
      for (int m = 1; m <= 32; m <<= 1) part += __shfl_xor(part, m, 64);
      if ((t & 63) == 0) red2[t >> 6] = part;
    }
    __syncthreads();

    const float sig = sigmoid_f(red2[0] + red2[1] + b2s);
    if (it == 10) { sig_last = sig; break; }

    if (t < nH) dz1S[t] = sig * (1.f - sig) * w2t * gelu_grad_f(z1);
    __syncthreads();

    // ---- bf16 backward: 4-h unroll, b128 LDS broadcast, pk-fma ----
    f32x2 g2 = {0.f, 0.f};
    #pragma unroll 4
    for (int h4 = 0; h4 < 32; ++h4) {
      const int h = 4 * h4;
      const f32x4 dz4 = *reinterpret_cast<const f32x4*>(&dz1S[h]);
      #pragma unroll
      for (int k = 0; k < 4; ++k) {
        const uint32_t w = w1tb2[(size_t)(h + k) * 1024 + t];
        const f32x2 wv = {bflo(w), bfhi(w)};
        g2 += dz4[k] * wv;
      }
    }
    const float gx = g2.x, gy = g2.y;
    const float sg0 = (gx > 0.f) ? 1.f : ((gx < 0.f) ? -1.f : 0.f);
    const float sg1 = (gy > 0.f) ? 1.f : ((gy < 0.f) ? -1.f : 0.f);
    const float p0 = pooledS[2 * t], p1 = pooledS[2 * t + 1];
    float d0 = fminf(fmaxf((xaS[2 * t]     - 0.01f * sg0) - p0, -0.2f), 0.2f);
    float d1 = fminf(fmaxf((xaS[2 * t + 1] - 0.01f * sg1) - p1, -0.2f), 0.2f);
    xaS[2 * t]     = p0 + d0;
    xaS[2 * t + 1] = p1 + d1;
    __syncthreads();
  }

  if (t == 0) scores[b] = sig_last;
}

// ---------- zero helper (graph-capture safe; fallback path only) ----------
__global__ __launch_bounds__(256) void k_zero(float* __restrict__ p, int n) {
  const int i = blockIdx.x * 256 + threadIdx.x;
  if (i < n) p[i] = 0.f;
}

// ---------- tail outputs ----------
__global__ __launch_bounds__(64) void k_finalize(
    const float* __restrict__ scores, float* __restrict__ out)
{
  const int t = threadIdx.x;  // 0..63
  const float s = scores[t];
  out[X_ELEMS + t] = s;                    // worst_score
  out[X_ELEMS + nB + t] = 1.0f - s;        // cert_score
  float m = s;
  for (int o = 32; o > 0; o >>= 1) m = fminf(m, __shfl_xor(m, o, 64));
  if (t == 0) out[X_ELEMS + 2 * nB] = (m < 0.1f) ? 1.0f : 0.0f;  // violated
}

extern "C" void kernel_launch(void* const* d_in, const int* in_sizes, int n_in,
                              void* d_out, int out_size, void* d_ws, size_t ws_size,
                              hipStream_t stream) {
  const float* x  = (const float*)d_in[0];
  const float* W1 = (const float*)d_in[1];
  const float* b1 = (const float*)d_in[2];
  const float* W2 = (const float*)d_in[3];
  const float* b2 = (const float*)d_in[4];
  float* out = (float*)d_out;
  float* ws = (float*)d_ws;

  constexpr size_t PMEAN_ELEMS  = (size_t)nB * NT * nD;   // 2,097,152 f32
  constexpr size_t POOLED_ELEMS = (size_t)nB * nD;        // 131,072 f32
  constexpr size_t W1_ELEMS     = (size_t)nD * nH;        // 262,144
  const size_t primary_bytes =
      PMEAN_ELEMS * 4 + W1_ELEMS * 2 * 2 + nB * 4;

  if (ws_size >= primary_bytes) {
    float*    pmean  = ws;
    uint16_t* w1b    = (uint16_t*)(ws + PMEAN_ELEMS);
    uint16_t* w1tb   = w1b + W1_ELEMS;
    float*    scores = (float*)(w1tb + W1_ELEMS);

    k_prep<<<dim3(32, 2), 256, 0, stream>>>(W1, w1b, w1tb);
    k_copy_mean<<<nB * NT, 512, 0, stream>>>(x, out, pmean);
    k_pgd<<<nB, 1024, 0, stream>>>(W1, w1b, w1tb, b1, W2, b2,
                                   pmean, nullptr, scores, 1);
    k_finalize<<<1, 64, 0, stream>>>(scores, out);
  } else {
    float*    pooled = ws;
    uint16_t* w1b    = (uint16_t*)(ws + POOLED_ELEMS);
    uint16_t* w1tb   = w1b + W1_ELEMS;
    float*    scores = (float*)(w1tb + W1_ELEMS);

    k_zero<<<(int)(POOLED_ELEMS + 255) / 256, 256, 0, stream>>>(
        pooled, (int)POOLED_ELEMS);
    k_prep<<<dim3(32, 2), 256, 0, stream>>>(W1, w1b, w1tb);
    k_copy_mean_atomic<<<nB * NT, 256, 0, stream>>>(x, out, pooled);
    k_pgd<<<nB, 1024, 0, stream>>>(W1, w1b, w1tb, b1, W2, b2,
                                   nullptr, pooled, scores, 0);
    k_finalize<<<1, 64, 0, stream>>>(scores, out);
  }
}